// Round 10
// baseline (127.672 us; speedup 1.0000x reference)
//
#include <hip/hip_runtime.h>
#include <stdint.h>

// TimestepPermutationQuantizer — PASSED r8/r9 with absmax 0.0. The arithmetic
// chain below is BIT-EXACT vs the harness golden and must not change:
//   scale = fmaxf(mx-mn, 1e-5f) * (1.0f/15.0f)   // XLA const-div rewrite
//   base  = clip(rintf(-mn/scale), 0, 15)        // IEEE f32 div, half-even
//   q     = clip(rintf(v/scale) + base, 0, 15)   // IEEE f32 div
//   out   = (q - base) * scale
// Partition P1: group g members = {gat[g*128+k]} with gat = d_in[1];
// channel c's group = asn[c]>>7 with asn = d_in[2].
//
// r9 -> r10 (dataflow only): kill the dominant LDS bank conflicts.
// r8 profile: SQ_LDS_BANK_CONFLICT = 5.36M cyc, mostly the per-element
// sb[g] ds_read_b64 (64 lanes x random group over a 256B region). Now:
// one ds_read_b64 of sb[lane&31] per thread per row (<=2-way = free),
// then per-element (s,b) via __shfl(sreg/breg, g) -> ds_bpermute, which
// uses the LDS crossbar and is conflict-free for arbitrary index patterns.

constexpr int C     = 4096;
constexpr int GS    = 128;
constexpr int NG    = C / GS;          // 32 groups
constexpr int BLOCK = 512;             // 8 waves
constexpr int WAVES = BLOCK / 64;
constexpr int GPW   = NG / WAVES;      // 4 groups per wave
constexpr int VECS  = C / 4 / BLOCK;   // 2 float4 per thread

typedef const __attribute__((address_space(1))) uint32_t glb_u32;
typedef __attribute__((address_space(3))) uint32_t lds_u32;

__device__ __forceinline__ void stage_row(const float* __restrict__ src,
                                          float* dst, int wave, int lane) {
    // DMA one 16 KiB row: per wave 2 chunks of 64 lanes x 16 B.
    // LDS dest = wave-uniform base + lane*16 (HW rule); global src per-lane.
    #pragma unroll
    for (int i = 0; i < 2; ++i) {
        const float* g = src + i * 2048 + wave * 256 + lane * 4;
        float*       l = dst + i * 2048 + wave * 256;
        __builtin_amdgcn_global_load_lds((glb_u32*)(uintptr_t)g,
                                         (lds_u32*)(uintptr_t)l, 16, 0, 0);
    }
}

__global__ __launch_bounds__(BLOCK, 8) void tpq_kernel(
    const float* __restrict__ x,
    const int*   __restrict__ gat,   // d_in[1]: group g = {gat[g*128+k]}
    const int*   __restrict__ asn,   // d_in[2]: channel c -> pos asn[c]
    float*       __restrict__ out,
    int rows)
{
    __shared__ float  rowbuf[2][C];
    __shared__ float2 sb[NG];

    const int tid  = threadIdx.x;
    const int wave = tid >> 6;
    const int lane = tid & 63;

    // ---- row-invariant preloads (once per block) ----
    int pidx0[GPW], pidx1[GPW];
    #pragma unroll
    for (int gi = 0; gi < GPW; ++gi) {
        const int g = wave * GPW + gi;
        pidx0[gi] = gat[g * GS + lane];
        pidx1[gi] = gat[g * GS + 64 + lane];
    }
    uint32_t gpack[VECS];                      // 4x 5-bit group ids per u32
    #pragma unroll
    for (int i = 0; i < VECS; ++i) {
        const int4 a = reinterpret_cast<const int4*>(asn)[tid + i * BLOCK];
        gpack[i] = (uint32_t)(a.x >> 7)        | ((uint32_t)(a.y >> 7) << 8)
                 | ((uint32_t)(a.z >> 7) << 16) | ((uint32_t)(a.w >> 7) << 24);
    }

    int r = blockIdx.x;
    if (r >= rows) return;
    stage_row(x + (size_t)r * C, rowbuf[0], wave, lane);
    int cur = 0;

    while (true) {
        __syncthreads();   // rowbuf[cur] staged (vmcnt drained + barrier);
                           // also: all waves done with sb/rowbuf of prev iter
        const int  rn = r + gridDim.x;
        const bool hn = rn < rows;
        if (hn) stage_row(x + (size_t)rn * C, rowbuf[cur ^ 1], wave, lane);

        // ---- P2: per-group min/max -> (scale, base), wave-per-group ----
        const float* rc = rowbuf[cur];
        #pragma unroll
        for (int gi = 0; gi < GPW; ++gi) {
            const float v0 = rc[pidx0[gi]];
            const float v1 = rc[pidx1[gi]];
            float mx = fmaxf(v0, v1);
            float mn = fminf(v0, v1);
            #pragma unroll
            for (int off = 32; off; off >>= 1) {
                mx = fmaxf(mx, __shfl_xor(mx, off));
                mn = fminf(mn, __shfl_xor(mn, off));
            }
            if (lane == 0) {
                const float s = fmaxf(mx - mn, 1e-5f) * (1.0f / 15.0f);
                const float b = fminf(fmaxf(rintf(-mn / s), 0.0f), 15.0f);
                sb[wave * GPW + gi] = make_float2(s, b);
            }
        }
        __syncthreads();   // sb visible (also drains next-row DMA — ok)

        // ---- broadcast sb into lane registers: one clean b64 per thread ---
        const float2 pl   = sb[lane & 31];   // lanes 0..31 hold groups 0..31
        const float  sreg = pl.x, breg = pl.y;

        // ---- P3: linear elementwise quant/dequant, fully coalesced ----
        const float4* rc4 = reinterpret_cast<const float4*>(rc);
        float4*       or4 = reinterpret_cast<float4*>(out + (size_t)r * C);
        #pragma unroll
        for (int i = 0; i < VECS; ++i) {
            const float4   v  = rc4[tid + i * BLOCK];   // conflict-free b128
            const uint32_t gp = gpack[i];
            float4 o;
            { const int g = gp & 31u;
              const float s = __shfl(sreg, g), b = __shfl(breg, g);
              o.x = (fminf(fmaxf(rintf(v.x / s) + b, 0.0f), 15.0f) - b) * s; }
            { const int g = (gp >> 8) & 31u;
              const float s = __shfl(sreg, g), b = __shfl(breg, g);
              o.y = (fminf(fmaxf(rintf(v.y / s) + b, 0.0f), 15.0f) - b) * s; }
            { const int g = (gp >> 16) & 31u;
              const float s = __shfl(sreg, g), b = __shfl(breg, g);
              o.z = (fminf(fmaxf(rintf(v.z / s) + b, 0.0f), 15.0f) - b) * s; }
            { const int g = (gp >> 24) & 31u;
              const float s = __shfl(sreg, g), b = __shfl(breg, g);
              o.w = (fminf(fmaxf(rintf(v.w / s) + b, 0.0f), 15.0f) - b) * s; }
            or4[tid + i * BLOCK] = o;
        }

        if (!hn) break;
        r = rn;
        cur ^= 1;
    }
}

extern "C" void kernel_launch(void* const* d_in, const int* in_sizes, int n_in,
                              void* d_out, int out_size, void* d_ws, size_t ws_size,
                              hipStream_t stream) {
    const float* x   = (const float*)d_in[0];
    const int*   gat = (const int*)d_in[1];   // perm (gather) — P1 partition
    const int*   asn = (const int*)d_in[2];   // inverse perm (assignment)
    float* out = (float*)d_out;

    const int rows = in_sizes[0] / C;            // 16384
    const int nblk = rows < 2048 ? rows : 2048;  // 8 rows/block grid-stride

    tpq_kernel<<<nblk, BLOCK, 0, stream>>>(x, gat, asn, out, rows);
}

// Round 11
// 104.694 us; speedup vs baseline: 1.2195x; 1.2195x over previous
//
#include <hip/hip_runtime.h>
#include <stdint.h>

// TimestepPermutationQuantizer — PASSED r8/r9/r10 with absmax 0.0. The
// arithmetic chain below is BIT-EXACT vs the harness golden — DO NOT CHANGE:
//   scale = fmaxf(mx-mn, 1e-5f) * (1.0f/15.0f)   // XLA const-div rewrite
//   base  = clip(rintf(-mn/scale), 0, 15)        // IEEE f32 div, half-even
//   q     = clip(rintf(v/scale) + base, 0, 15)   // IEEE f32 div
//   out   = (q - base) * scale
// Partition P1: group g members = {gat[g*128+k]}, gat = d_in[1];
// channel c's group = asn[c]>>7, asn = d_in[2].
//
// Perf log: r8 125.5 (3 barriers, explicit staging) -> r9 118.7 (DMA+dbuf,
// 2 barriers) -> r10 127.7 (REGRESSED: shfl-based sb lookup ADDED DS ops;
// __shfl is an LDS-pipe op, not free).
// r11: cut DS-pipe ops 66 -> 26 per thread-row:
//  - P2: 16 lanes/group x 8 elems/lane; in-lane VALU min/max tree (14 ops)
//    + 4 shuffle levels (was 6 levels x 4 groups serial = 48 shfl -> 8)
//  - sb-publish via raw `s_waitcnt lgkmcnt(0); s_barrier` (no vmcnt drain):
//    next-row DMA stays in flight across P2+P3; full __syncthreads() only
//    at loop bottom. sb double-buffered for safety.
//  - P3 identical to r9 (b64 sb reads beat shfl — r10's lesson).

constexpr int C     = 4096;
constexpr int GS    = 128;
constexpr int NG    = C / GS;          // 32 groups
constexpr int BLOCK = 512;             // 8 waves
constexpr int WAVES = BLOCK / 64;
constexpr int GPW   = NG / WAVES;      // 4 groups per wave (concurrent)
constexpr int EPL   = GS / 16;         // 8 elements per lane in P2
constexpr int VECS  = C / 4 / BLOCK;   // 2 float4 per thread in P3

typedef const __attribute__((address_space(1))) uint32_t glb_u32;
typedef __attribute__((address_space(3))) uint32_t lds_u32;

__device__ __forceinline__ void stage_row(const float* __restrict__ src,
                                          float* dst, int wave, int lane) {
    // DMA one 16 KiB row: per wave 2 chunks of 64 lanes x 16 B.
    // LDS dest = wave-uniform base + lane*16 (HW rule); global src per-lane.
    #pragma unroll
    for (int i = 0; i < 2; ++i) {
        const float* g = src + i * 2048 + wave * 256 + lane * 4;
        float*       l = dst + i * 2048 + wave * 256;
        __builtin_amdgcn_global_load_lds((glb_u32*)(uintptr_t)g,
                                         (lds_u32*)(uintptr_t)l, 16, 0, 0);
    }
}

__global__ __launch_bounds__(BLOCK, 8) void tpq_kernel(
    const float* __restrict__ x,
    const int*   __restrict__ gat,   // d_in[1]: group g = {gat[g*128+k]}
    const int*   __restrict__ asn,   // d_in[2]: channel c -> pos asn[c]
    float*       __restrict__ out,
    int rows)
{
    __shared__ float  rowbuf[2][C];
    __shared__ float2 sb[2][NG];

    const int tid  = threadIdx.x;
    const int wave = tid >> 6;
    const int lane = tid & 63;
    const int sub  = lane >> 4;        // which of 4 groups in this wave
    const int sl   = lane & 15;        // lane within 16-lane subgroup
    const int g    = wave * GPW + sub; // this lane's P2 group

    // ---- row-invariant preloads (once per block) ----
    int pidx[EPL];                     // 8 consecutive perm entries
    {
        const int4* g4 = reinterpret_cast<const int4*>(gat + g * GS + sl * EPL);
        const int4 a = g4[0], b = g4[1];
        pidx[0] = a.x; pidx[1] = a.y; pidx[2] = a.z; pidx[3] = a.w;
        pidx[4] = b.x; pidx[5] = b.y; pidx[6] = b.z; pidx[7] = b.w;
    }
    uint32_t gpack[VECS];              // 4x 5-bit group ids per u32
    #pragma unroll
    for (int i = 0; i < VECS; ++i) {
        const int4 a = reinterpret_cast<const int4*>(asn)[tid + i * BLOCK];
        gpack[i] = (uint32_t)(a.x >> 7)        | ((uint32_t)(a.y >> 7) << 8)
                 | ((uint32_t)(a.z >> 7) << 16) | ((uint32_t)(a.w >> 7) << 24);
    }

    int r = blockIdx.x;
    stage_row(x + (size_t)r * C, rowbuf[0], wave, lane);
    __syncthreads();                   // own-DMA vmcnt drained + barrier
    int cur = 0;

    while (true) {
        const int  rn = r + gridDim.x;
        const bool hn = rn < rows;
        if (hn) stage_row(x + (size_t)rn * C, rowbuf[cur ^ 1], wave, lane);
        // ^ stays in flight through P2 AND P3 (raw barrier below skips vmcnt)

        // ---- P2: 16 lanes/group, 8 elems/lane; VALU tree + 4 shfl levels --
        const float* rc = rowbuf[cur];
        float v0 = rc[pidx[0]], v1 = rc[pidx[1]], v2 = rc[pidx[2]], v3 = rc[pidx[3]];
        float v4 = rc[pidx[4]], v5 = rc[pidx[5]], v6 = rc[pidx[6]], v7 = rc[pidx[7]];
        float mx = fmaxf(fmaxf(fmaxf(v0, v1), fmaxf(v2, v3)),
                         fmaxf(fmaxf(v4, v5), fmaxf(v6, v7)));
        float mn = fminf(fminf(fminf(v0, v1), fminf(v2, v3)),
                         fminf(fminf(v4, v5), fminf(v6, v7)));
        #pragma unroll
        for (int off = 8; off; off >>= 1) {   // stays inside 16-lane subgroup
            mx = fmaxf(mx, __shfl_xor(mx, off));
            mn = fminf(mn, __shfl_xor(mn, off));
        }
        if (sl == 0) {
            const float s = fmaxf(mx - mn, 1e-5f) * (1.0f / 15.0f);
            const float b = fminf(fmaxf(rintf(-mn / s), 0.0f), 15.0f);
            sb[cur][g] = make_float2(s, b);
        }

        // ---- publish sb: LDS-only drain + raw barrier (DMA NOT drained) ---
        asm volatile("s_waitcnt lgkmcnt(0)\n\ts_barrier" ::: "memory");

        // ---- P3: linear elementwise quant/dequant, fully coalesced ----
        const float4*  rc4 = reinterpret_cast<const float4*>(rc);
        const float2*  sbc = sb[cur];
        float4*        or4 = reinterpret_cast<float4*>(out + (size_t)r * C);
        #pragma unroll
        for (int i = 0; i < VECS; ++i) {
            const float4   v  = rc4[tid + i * BLOCK];   // conflict-free b128
            const uint32_t gp = gpack[i];
            float4 o;
            { const float2 p = sbc[gp & 31u];
              o.x = (fminf(fmaxf(rintf(v.x / p.x) + p.y, 0.0f), 15.0f) - p.y) * p.x; }
            { const float2 p = sbc[(gp >> 8) & 31u];
              o.y = (fminf(fmaxf(rintf(v.y / p.x) + p.y, 0.0f), 15.0f) - p.y) * p.x; }
            { const float2 p = sbc[(gp >> 16) & 31u];
              o.z = (fminf(fmaxf(rintf(v.z / p.x) + p.y, 0.0f), 15.0f) - p.y) * p.x; }
            { const float2 p = sbc[(gp >> 24) & 31u];
              o.w = (fminf(fmaxf(rintf(v.w / p.x) + p.y, 0.0f), 15.0f) - p.y) * p.x; }
            or4[tid + i * BLOCK] = o;
        }

        if (!hn) break;
        r = rn;
        cur ^= 1;
        __syncthreads();   // full drain: DMA(rn) landed; all waves past P3
    }
}

extern "C" void kernel_launch(void* const* d_in, const int* in_sizes, int n_in,
                              void* d_out, int out_size, void* d_ws, size_t ws_size,
                              hipStream_t stream) {
    const float* x   = (const float*)d_in[0];
    const int*   gat = (const int*)d_in[1];   // perm (gather) — P1 partition
    const int*   asn = (const int*)d_in[2];   // inverse perm (assignment)
    float* out = (float*)d_out;

    const int rows = in_sizes[0] / C;            // 16384
    const int nblk = rows < 2048 ? rows : 2048;  // 8 rows/block grid-stride

    tpq_kernel<<<nblk, BLOCK, 0, stream>>>(x, gat, asn, out, rows);
}